// Round 7
// baseline (288.736 us; speedup 1.0000x reference)
//
#include <hip/hip_runtime.h>
#include <hip/hip_fp16.h>

#define HD 64
#define FIN 32
#define NG 1024
#define STRIDE 68   // col bucket: int0 = deg counter, ints 4..67 = neighbor slots (16B-aligned)
#define SLOT0 4     // first neighbor slot (keeps int4 loads 16B-aligned: 272*v+16 ≡ 0 mod 16)

typedef _Float16 f16x8 __attribute__((ext_vector_type(8)));
typedef float f32x4 __attribute__((ext_vector_type(4)));

// feature mapping for MFMA D-tiles (jt, c=lane&15):  jt<2 -> 2c+jt ; jt>=2 -> 32+2c+(jt-2)
// -> lane packs (jt0,jt1) and (jt2,jt3) as adjacent half2 pairs => line-aligned 4B stores.
__device__ __forceinline__ int fmap(int jt, int c) {
    return (jt < 2) ? (2 * c + jt) : (32 + 2 * c + (jt - 2));
}

// ================= init: zero bucket counters + the shared zero-row =================
__global__ void k_zero(int* __restrict__ col, float* __restrict__ B16zr, int N) {
    int v = blockIdx.x * blockDim.x + threadIdx.x;
    if (v < N) col[(size_t)v * STRIDE] = 0;
    if (blockIdx.x == 0 && threadIdx.x < 32) B16zr[threadIdx.x] = 0.f;  // 128B zero row
}

// ================= CSR fill — counter embedded in bucket line =================
// pos = atomicAdd(&col[d*STRIDE]) allocates the slot AND counts the degree.
// Atomic-line-write bound: 1M atomics x 64B write-through = 60MB @ ~1.1TB/s
// = ~56-62us floor (confirmed R1/R2/R4/R5/R6). Keep PURE (R3: fusing regressed).
__global__ void k_fill(const int* __restrict__ src, const int* __restrict__ dst,
                       int* __restrict__ col, int E) {
    int e = blockIdx.x * blockDim.x + threadIdx.x;
    if (e < E) {
        int d = dst[e];
        int pos = atomicAdd(&col[(size_t)d * STRIDE], 1);
        if (pos < STRIDE - SLOT0) col[(size_t)d * STRIDE + SLOT0 + pos] = src[e];
    }
}

// ================= W_convs -> fp16 MFMA B-frag order (new feature mapping) =================
// Wf[layer][(jt*2+kh)*64*8 + lane*8 + t] = W[layer][kh*32+(lane>>4)*8+t][fmap(jt, lane&15)]
__global__ void k_wconv(const float* __restrict__ W, __half* __restrict__ Wf, int total) {
    int tid = blockIdx.x * blockDim.x + threadIdx.x;
    if (tid >= total) return;
    int layer = tid >> 12;
    int r = tid & 4095;
    int frag = r >> 9;
    int lane = (r >> 3) & 63;
    int t = r & 7;
    int jt = frag >> 1, kh = frag & 1;
    int k = kh * 32 + (lane >> 4) * 8 + t;
    int n = fmap(jt, lane & 15);
    Wf[tid] = (_Float16)W[(size_t)layer * 4096 + k * 64 + n];
}

// ================= W_emb (32x64) -> fp16 MFMA B-frag order (K=32) =================
__global__ void k_wemb(const float* __restrict__ W, __half* __restrict__ Wef) {
    int tid = blockIdx.x * blockDim.x + threadIdx.x;
    if (tid >= 2048) return;
    int jt = tid >> 9;
    int lane = (tid >> 3) & 63;
    int t = tid & 7;
    int k = (lane >> 4) * 8 + t;
    int n = fmap(jt, lane & 15);
    Wef[tid] = (_Float16)W[k * HD + n];
}

// ================= MFMA embedding: A16 = half(relu(x@Wemb+b)), + dinv =================
__global__ __launch_bounds__(256) void k_emb_mfma(const float* __restrict__ x,
                                                  const float4* __restrict__ Wef4,
                                                  const float* __restrict__ bemb,
                                                  const int* __restrict__ col,
                                                  __half* __restrict__ A16,
                                                  float* __restrict__ dinv, int N) {
    int t = threadIdx.x;
    int lane = t & 63;
    int wv = t >> 6;
    int node0 = blockIdx.x * 64 + wv * 16;
    int m = lane & 15, kq = lane >> 4;

    int vm = node0 + m;
    if (vm > N - 1) vm = N - 1;  // clamp (store is guarded)
    const float4* xr = (const float4*)(x + (size_t)vm * FIN + kq * 8);
    float4 xa = xr[0], xb = xr[1];
    f16x8 a;
    a[0] = (_Float16)xa.x; a[1] = (_Float16)xa.y; a[2] = (_Float16)xa.z; a[3] = (_Float16)xa.w;
    a[4] = (_Float16)xb.x; a[5] = (_Float16)xb.y; a[6] = (_Float16)xb.z; a[7] = (_Float16)xb.w;

    union U { float4 f; f16x8 h; };
    f32x4 acc[4];
#pragma unroll
    for (int jt = 0; jt < 4; jt++) {
        U b; b.f = Wef4[jt * 64 + lane];
        acc[jt] = (f32x4){0.f, 0.f, 0.f, 0.f};
        acc[jt] = __builtin_amdgcn_mfma_f32_16x16x32_f16(a, b.h, acc[jt], 0, 0, 0);
    }
    float b01x = bemb[2 * m], b01y = bemb[2 * m + 1];
    float b23x = bemb[32 + 2 * m], b23y = bemb[32 + 2 * m + 1];
#pragma unroll
    for (int r = 0; r < 4; r++) {
        int v = node0 + kq * 4 + r;
        if (v < N) {
            __half2 p01 = __floats2half2_rn(fmaxf(acc[0][r] + b01x, 0.f),
                                            fmaxf(acc[1][r] + b01y, 0.f));
            __half2 p23 = __floats2half2_rn(fmaxf(acc[2][r] + b23x, 0.f),
                                            fmaxf(acc[3][r] + b23y, 0.f));
            *(__half2*)(A16 + (size_t)v * HD + 2 * m) = p01;
            *(__half2*)(A16 + (size_t)v * HD + 32 + 2 * m) = p23;
            if (m == 0) dinv[v] = rsqrtf((float)(col[(size_t)v * STRIDE] + 1));
        }
    }
}

// ================= MFMA fp16 GEMM: B16[v] = half((A16[v] @ W) * dinv[v]) =================
__global__ __launch_bounds__(256) void k_gemm_mfma(const float4* __restrict__ A16f4,
                                                   const float4* __restrict__ Wf4,
                                                   const float* __restrict__ dinv,
                                                   __half* __restrict__ B16, int N) {
    int t = threadIdx.x;
    int lane = t & 63;
    int wv = t >> 6;
    int node0 = blockIdx.x * 64 + wv * 16;
    int lm = lane & 15, kq = lane >> 4;

    union U { float4 f; f16x8 h; };
    U a0, a1;
    size_t arow = (size_t)(node0 + lm) * 8;
    a0.f = A16f4[arow + kq];
    a1.f = A16f4[arow + 4 + kq];

    f32x4 acc[4];
#pragma unroll
    for (int jt = 0; jt < 4; jt++) acc[jt] = (f32x4){0.f, 0.f, 0.f, 0.f};
#pragma unroll
    for (int jt = 0; jt < 4; jt++) {
        U b0, b1;
        b0.f = Wf4[(jt * 2 + 0) * 64 + lane];
        b1.f = Wf4[(jt * 2 + 1) * 64 + lane];
        acc[jt] = __builtin_amdgcn_mfma_f32_16x16x32_f16(a0.h, b0.h, acc[jt], 0, 0, 0);
        acc[jt] = __builtin_amdgcn_mfma_f32_16x16x32_f16(a1.h, b1.h, acc[jt], 0, 0, 0);
    }
#pragma unroll
    for (int r = 0; r < 4; r++) {
        int v = node0 + kq * 4 + r;
        if (v < N) {
            float dv = dinv[v];
            __half2 p01 = __floats2half2_rn(acc[0][r] * dv, acc[1][r] * dv);
            __half2 p23 = __floats2half2_rn(acc[2][r] * dv, acc[3][r] * dv);
            *(__half2*)(B16 + (size_t)v * HD + 2 * lm) = p01;
            *(__half2*)(B16 + (size_t)v * HD + 32 + 2 * lm) = p23;
        }
    }
}

// ================= gather v3: direct broadcast index loads, no shuffles =================
// h_new[v] = relu(dinv[v] * (B[v] + sum_{src->v} B[src]) + bias)
// Quarter q loads its 4 neighbor indices with ONE 16B-aligned int4 load
// (16 lanes same address -> HW broadcast, ~1 line req); deg read the same way.
// R6 post-mortem: the shfl broadcasts (ds_permute) made gather LDS-pipe
// co-bound (~26us/CU); this removes 20 of 28 LDS-pipe ops per wave.
template <bool LAST>
__global__ __launch_bounds__(256) void k_gather(const __half2* __restrict__ B16,
                                                const int* __restrict__ col,
                                                const float* __restrict__ bias,
                                                __half2* __restrict__ houtH,
                                                float* __restrict__ houtF,
                                                const float* __restrict__ Wtgt,
                                                const float* __restrict__ btgt,
                                                float* __restrict__ tgt, int N, int ZR) {
    int t = threadIdx.x;
    int lane = t & 63;
    int q = lane >> 4, p = lane & 15;
    int v = blockIdx.x * 4 + (t >> 6);
    if (v >= N) return;

    const int* bucket = col + (size_t)v * STRIDE;
    int degraw = bucket[0];                       // same-addr broadcast load
    int deg = degraw > STRIDE - SLOT0 ? STRIDE - SLOT0 : degraw;
    int tot = deg + 1;  // + self

    float2 a0 = make_float2(0.f, 0.f), a1 = make_float2(0.f, 0.f);
    {
        int4 iq = *(const int4*)(bucket + SLOT0 + 4 * q);  // rows 4q..4q+3, broadcast
        int idx[4] = {iq.x, iq.y, iq.z, iq.w};
#pragma unroll
        for (int r = 0; r < 4; r++) {
            int i = 4 * q + r;
            idx[r] = (i < deg) ? idx[r] : ((i == deg) ? v : ZR);
        }
        float2 raw[4];
#pragma unroll
        for (int r = 0; r < 4; r++)
            raw[r] = *(const float2*)(B16 + (size_t)idx[r] * 32 + p * 2);
#pragma unroll
        for (int r = 0; r < 4; r++) {
            float2 f0 = __half22float2(((const __half2*)&raw[r])[0]);
            float2 f1 = __half22float2(((const __half2*)&raw[r])[1]);
            a0.x += f0.x; a0.y += f0.y; a1.x += f1.x; a1.y += f1.y;
        }
    }
    for (int b0 = 16; b0 < tot; b0 += 16) {  // rare tail (deg > 15)
        int4 iq = *(const int4*)(bucket + SLOT0 + b0 + 4 * q);
        int idx[4] = {iq.x, iq.y, iq.z, iq.w};
#pragma unroll
        for (int r = 0; r < 4; r++) {
            int i = b0 + 4 * q + r;
            idx[r] = (i < deg) ? idx[r] : ((i == deg) ? v : ZR);
        }
        float2 raw[4];
#pragma unroll
        for (int r = 0; r < 4; r++)
            raw[r] = *(const float2*)(B16 + (size_t)idx[r] * 32 + p * 2);
#pragma unroll
        for (int r = 0; r < 4; r++) {
            float2 f0 = __half22float2(((const __half2*)&raw[r])[0]);
            float2 f1 = __half22float2(((const __half2*)&raw[r])[1]);
            a0.x += f0.x; a0.y += f0.y; a1.x += f1.x; a1.y += f1.y;
        }
    }
    // combine quarters (xor 16, 32) -> every lane holds full sums for feats [4p,4p+4)
    a0.x += __shfl_xor(a0.x, 16, 64); a0.y += __shfl_xor(a0.y, 16, 64);
    a1.x += __shfl_xor(a1.x, 16, 64); a1.y += __shfl_xor(a1.y, 16, 64);
    a0.x += __shfl_xor(a0.x, 32, 64); a0.y += __shfl_xor(a0.y, 32, 64);
    a1.x += __shfl_xor(a1.x, 32, 64); a1.y += __shfl_xor(a1.y, 32, 64);

    float dv = rsqrtf((float)(degraw + 1));
    float4 b4 = *(const float4*)(bias + 4 * p);
    float r0 = fmaxf(dv * a0.x + b4.x, 0.f);
    float r1 = fmaxf(dv * a0.y + b4.y, 0.f);
    float r2 = fmaxf(dv * a1.x + b4.z, 0.f);
    float r3 = fmaxf(dv * a1.y + b4.w, 0.f);
    if (LAST) {
        if (q == 0) *(float4*)(houtF + (size_t)v * HD + 4 * p) = make_float4(r0, r1, r2, r3);
        float4 w4 = *(const float4*)(Wtgt + 4 * p);
        float pp = r0 * w4.x + r1 * w4.y + r2 * w4.z + r3 * w4.w;
        pp += __shfl_xor(pp, 1, 64); pp += __shfl_xor(pp, 2, 64);
        pp += __shfl_xor(pp, 4, 64); pp += __shfl_xor(pp, 8, 64);
        if (lane == 0) tgt[v] = pp + btgt[0];
    } else {
        if (q == 0) {
            float2 st;
            ((__half2*)&st)[0] = __floats2half2_rn(r0, r1);
            ((__half2*)&st)[1] = __floats2half2_rn(r2, r3);
            *(float2*)(houtH + (size_t)v * 32 + 2 * p) = st;
        }
    }
}

// ================= mean pool + graph heads (float4, 16 rows/iter) =================
__global__ __launch_bounds__(256) void k_pool(const float* __restrict__ h,
                                              const int* __restrict__ batch,
                                              const float* __restrict__ Wact,
                                              const float* __restrict__ bact,
                                              const float* __restrict__ Watom,
                                              const float* __restrict__ batom,
                                              float* __restrict__ out_act,
                                              float* __restrict__ out_atom, int N) {
    int g = blockIdx.x;
    int t = threadIdx.x;
    int q = t >> 4, p = t & 15;
    int lo = 0, hi = N;
    while (lo < hi) { int mid = (lo + hi) >> 1; if (batch[mid] < g) lo = mid + 1; else hi = mid; }
    int s = lo;
    hi = N;
    while (lo < hi) { int mid = (lo + hi) >> 1; if (batch[mid] < g + 1) lo = mid + 1; else hi = mid; }
    int e2 = lo;
    float4 acc = make_float4(0.f, 0.f, 0.f, 0.f);
    for (int v = s + q; v < e2; v += 16) {
        float4 c = *(const float4*)(h + (size_t)v * HD + p * 4);
        acc.x += c.x; acc.y += c.y; acc.z += c.z; acc.w += c.w;
    }
    __shared__ float4 part[16][16];
    part[q][p] = acc;
    __syncthreads();
    __shared__ float pl[HD];
    if (t < 16) {
        float4 tot = part[0][t];
#pragma unroll
        for (int k = 1; k < 16; k++) {
            float4 c = part[k][t];
            tot.x += c.x; tot.y += c.y; tot.z += c.z; tot.w += c.w;
        }
        float cnt = fmaxf((float)(e2 - s), 1.f);
        pl[t * 4 + 0] = tot.x / cnt; pl[t * 4 + 1] = tot.y / cnt;
        pl[t * 4 + 2] = tot.z / cnt; pl[t * 4 + 3] = tot.w / cnt;
    }
    __syncthreads();
    if (t < 8) {
        float a = bact[t];
#pragma unroll
        for (int k = 0; k < HD; k++) a += pl[k] * Wact[k * 8 + t];
        out_act[g * 8 + t] = a;
    }
    if (t < 16) {
        float a = batom[t];
#pragma unroll
        for (int k = 0; k < HD; k++) a += pl[k] * Watom[k * 16 + t];
        out_atom[g * 16 + t] = a;
    }
}

extern "C" void kernel_launch(void* const* d_in, const int* in_sizes, int n_in,
                              void* d_out, int out_size, void* d_ws, size_t ws_size,
                              hipStream_t stream) {
    const float* x     = (const float*)d_in[0];
    const int*   ei    = (const int*)d_in[1];
    const int*   batch = (const int*)d_in[2];
    const float* Wemb  = (const float*)d_in[3];
    const float* bemb  = (const float*)d_in[4];
    const float* Wconv = (const float*)d_in[5];
    const float* bconv = (const float*)d_in[6];
    const float* Wact  = (const float*)d_in[7];
    const float* bact  = (const float*)d_in[8];
    const float* Wtgt  = (const float*)d_in[9];
    const float* btgt  = (const float*)d_in[10];
    const float* Watom = (const float*)d_in[11];
    const float* batom = (const float*)d_in[12];

    const int N = in_sizes[0] / FIN;
    const int E = in_sizes[1] / 2;
    const int L = in_sizes[5] / (HD * HD);
    const int Npad = (N + 63) & ~63;
    const int ZR = Npad;  // zero-row index in B16

    // workspace layout (~53 MB)
    __half* A16   = (__half*)d_ws;                       // Npad*64 halves
    __half* B16   = A16 + (size_t)Npad * HD;             // (Npad+64)*64 halves (row Npad = zeros)
    float*  dinv  = (float*)(B16 + (size_t)(Npad + 64) * HD);  // N f
    __half* Wf    = (__half*)(dinv + N);                 // L*4096 halves
    __half* Wef   = Wf + (size_t)L * 4096;               // 2048 halves (emb frags)
    int*    col   = (int*)(Wef + 2048);                  // N*STRIDE + pad ints

    const int* srcA = ei;       // edge_index[0] = message source
    const int* dstA = ei + E;   // edge_index[1] = aggregation target

    float* out_act  = (float*)d_out;
    float* out_tgt  = out_act + (size_t)NG * 8;
    float* out_atom = out_tgt + N;
    float* out_h    = out_atom + (size_t)NG * 16;

    const int nbN = (N + 255) / 256;
    const int nbE = (E + 255) / 256;
    const int nbW = (N + 3) / 4;
    const int nbG = (N + 63) / 64;
    const int wtotal = L * 4096;

    k_zero<<<nbN, 256, 0, stream>>>(col, (float*)(B16 + (size_t)ZR * HD), N);
    k_wconv<<<(wtotal + 255) / 256, 256, 0, stream>>>(Wconv, Wf, wtotal);
    k_wemb<<<8, 256, 0, stream>>>(Wemb, Wef);
    k_fill<<<nbE, 256, 0, stream>>>(srcA, dstA, col, E);
    k_emb_mfma<<<nbG, 256, 0, stream>>>(x, (const float4*)Wef, bemb, col, A16, dinv, N);

    for (int l = 0; l < L; ++l) {
        k_gemm_mfma<<<nbG, 256, 0, stream>>>((const float4*)A16,
                                             (const float4*)(Wf + (size_t)l * 4096),
                                             dinv, B16, N);
        if (l < L - 1)
            k_gather<false><<<nbW, 256, 0, stream>>>((const __half2*)B16, col,
                                                     bconv + l * HD, (__half2*)A16, nullptr,
                                                     Wtgt, btgt, out_tgt, N, ZR);
        else
            k_gather<true><<<nbW, 256, 0, stream>>>((const __half2*)B16, col,
                                                    bconv + l * HD, nullptr, out_h,
                                                    Wtgt, btgt, out_tgt, N, ZR);
    }
    k_pool<<<NG, 256, 0, stream>>>(out_h, batch, Wact, bact, Watom, batom, out_act, out_atom, N);
}